// Round 5
// baseline (380.889 us; speedup 1.0000x reference)
//
#include <hip/hip_runtime.h>
#include <math.h>

typedef unsigned short ushort_t;
typedef __attribute__((ext_vector_type(4))) float floatx4;
typedef __attribute__((ext_vector_type(8))) short bf16x8;

#define DIMC 1152
#define NHEADS 16
#define HDIM 72

__device__ __forceinline__ ushort_t f2bf(float f) {
  unsigned u = __float_as_uint(f);
  u += 0x7FFFu + ((u >> 16) & 1u);      // round-to-nearest-even
  return (ushort_t)(u >> 16);
}
__device__ __forceinline__ float bf2f(ushort_t s) {
  return __uint_as_float(((unsigned)s) << 16);
}

__device__ __forceinline__ void gload_lds16(const ushort_t* g, ushort_t* l) {
  __builtin_amdgcn_global_load_lds(
      (const __attribute__((address_space(1))) unsigned int*)(const void*)g,
      (__attribute__((address_space(3))) unsigned int*)(void*)l, 16, 0, 0);
}

__device__ __forceinline__ bf16x8 load_bf16x8(const ushort_t* p) {
  union { bf16x8 v; uint4 u; } t;
  t.u = *(const uint4*)p;
  return t.v;
}

// ---------------------------------------------------------------------------
// fp32 -> bf16 elementwise (8 elems/thread)
// ---------------------------------------------------------------------------
__global__ void cvt_bf16_kernel(const float* __restrict__ src,
                                ushort_t* __restrict__ dst, int n8) {
  int i = blockIdx.x * 256 + threadIdx.x;
  if (i >= n8) return;
  float4 f0 = ((const float4*)src)[2 * (size_t)i];
  float4 f1 = ((const float4*)src)[2 * (size_t)i + 1];
  union { ushort_t s[8]; uint4 u; } t;
  t.s[0] = f2bf(f0.x); t.s[1] = f2bf(f0.y); t.s[2] = f2bf(f0.z); t.s[3] = f2bf(f0.w);
  t.s[4] = f2bf(f1.x); t.s[5] = f2bf(f1.y); t.s[6] = f2bf(f1.z); t.s[7] = f2bf(f1.w);
  ((uint4*)dst)[i] = t.u;
}

// ---------------------------------------------------------------------------
// W [K][N] fp32  ->  Wt [N][K] bf16   (64x64 tiles via LDS)
// ---------------------------------------------------------------------------
__global__ void transpose_w_kernel(const float* __restrict__ W,
                                   ushort_t* __restrict__ Wt, int K, int N) {
  __shared__ ushort_t tile[64 * 80];
  int k0 = blockIdx.x * 64, n0 = blockIdx.y * 64;
  int tid = threadIdx.x;
  int kl = tid >> 4, n4 = tid & 15;
  for (int rr = 0; rr < 4; rr++) {
    int k = kl + rr * 16;
    float4 f = *(const float4*)(W + (size_t)(k0 + k) * N + n0 + n4 * 4);
    tile[(n4 * 4 + 0) * 80 + k] = f2bf(f.x);
    tile[(n4 * 4 + 1) * 80 + k] = f2bf(f.y);
    tile[(n4 * 4 + 2) * 80 + k] = f2bf(f.z);
    tile[(n4 * 4 + 3) * 80 + k] = f2bf(f.w);
  }
  __syncthreads();
  int nl = tid >> 2, kq = tid & 3;
  uint4 v0 = *(const uint4*)(tile + nl * 80 + kq * 16);
  uint4 v1 = *(const uint4*)(tile + nl * 80 + kq * 16 + 8);
  *(uint4*)(Wt + (size_t)(n0 + nl) * K + k0 + kq * 16) = v0;
  *(uint4*)(Wt + (size_t)(n0 + nl) * K + k0 + kq * 16 + 8) = v1;
}

// ---------------------------------------------------------------------------
// 128x128 GEMM, BK=64, ks-split 2-phase schedule. 256 threads (4 waves 2x2,
// per-wave 64x64 = acc[4][4]). LDS 64 KiB = 2 bufs x {A[2ks][128][32],
// B[2ks][128][32]} -> 2 blocks/CU.
// Round-4 post-mortem: 3-deep prefetch was NULL -> not latency-bound; the
// cost is barriers/lgkm per MFMA (4 barriers per 16 MFMA). This version
// keeps the same verified 2-barrier-per-phase skeleton but doubles the
// MFMA per phase: phase ks reads the ks half-slab (8 ds_read_b128) and
// runs 16 MFMAs -> 4 barriers per 32 MFMA (2x amortization).
// Counted-vmcnt staging (never drains in main loop): phase ks of tile t
// issues half-slab H(t+1,ks) (4 loads: A+B of K-half ks); EVERY phase ends
// with vmcnt(4), retiring the slab issued one full tile earlier (slack =
// 1 tile > L2/L3-hit latency; staging is cache-served, HBM fetch ~60MB).
//   end ph0(t): outstanding = H(t,1)+H(t+1,0) -> vmcnt(4) retires H(t,1)
//   end ph1(t): outstanding = H(t+1,0)+H(t+1,1) -> vmcnt(4) retires H(t+1,0)
// Write-safety: H(t+1,*) lands in buf (t+1)&1, whose readers (tile t-1)
// drained at their lgkmcnt(0) before the tile-(t-1)-final barrier, which
// precedes any issue in tile t.
// XOR swizzle: src pre-swizzled for global_load_lds linear dst; reads
// apply the same XOR -> conflict-free ds_read_b128 (unchanged layout).
// Two independent problem segments routed by block id (merges the Q and
// KV projections into one dispatch). Grid must be %8 == 0 for XCD swizzle.
// ---------------------------------------------------------------------------
template <bool OUT_F32>
__global__ __launch_bounds__(256, 2) void gemm128_kernel(
    const ushort_t* __restrict__ A0, const ushort_t* __restrict__ Bt0,
    const float* __restrict__ bias0, void* __restrict__ C0,
    int NTn0, int Ncols0,
    const ushort_t* __restrict__ A1, const ushort_t* __restrict__ Bt1,
    const float* __restrict__ bias1, void* __restrict__ C1,
    int NTn1, int Ncols1,
    int nblk0, int Kdim) {
  __shared__ ushort_t S[32768];  // 64 KiB: buf*16384 + ks*4096 + {A:0, B:8192}

  int lin = blockIdx.x;
  int cpx = gridDim.x >> 3;
  int wg = (lin & 7) * cpx + (lin >> 3);   // XCD-contiguous chunks

  const ushort_t* Aseg; const ushort_t* Bseg;
  const float* bias; void* Cptr; int NTn, Ncols;
  if (wg < nblk0) {
    Aseg = A0; Bseg = Bt0; bias = bias0; Cptr = C0; NTn = NTn0; Ncols = Ncols0;
  } else {
    wg -= nblk0;
    Aseg = A1; Bseg = Bt1; bias = bias1; Cptr = C1; NTn = NTn1; Ncols = Ncols1;
  }
  int mt = wg / NTn, nt = wg % NTn;
  int m0 = mt * 128, n0 = nt * 128;

  int tid = threadIdx.x;
  int wid = tid >> 6, lane = tid & 63, quad = lane >> 4, l16 = lane & 15;
  int wr = wid >> 1, wc = wid & 1;
  const int qoff = (quad * 8) ^ ((l16 & 8) << 1);  // swizzled read col (ushorts)

  // staging source coords (per thread), pre-swizzled; one call = 64 rows x 32k
  const int srow = tid >> 2;                                   // 0..63
  const int scol = ((tid & 3) * 8) ^ ((tid & 32) ? 16 : 0);    // ushorts
  const ushort_t* Abase = Aseg + (size_t)m0 * Kdim;
  const ushort_t* Bbase = Bseg + (size_t)n0 * Kdim;

  // H(t,ks) = A(t,ks)+B(t,ks) = 4 load instructions
  auto stageA = [&](int t, int ks) {
    const ushort_t* src = Abase + (size_t)srow * Kdim + t * 64 + ks * 32 + scol;
    ushort_t* dst = S + (t & 1) * 16384 + ks * 4096 + (tid >> 6) * 512;
    gload_lds16(src, dst);                             // rows 0..63
    gload_lds16(src + (size_t)64 * Kdim, dst + 2048);  // rows 64..127
  };
  auto stageB = [&](int t, int ks) {
    const ushort_t* src = Bbase + (size_t)srow * Kdim + t * 64 + ks * 32 + scol;
    ushort_t* dst = S + (t & 1) * 16384 + 8192 + ks * 4096 + (tid >> 6) * 512;
    gload_lds16(src, dst);
    gload_lds16(src + (size_t)64 * Kdim, dst + 2048);
  };

  floatx4 zero = {0.f, 0.f, 0.f, 0.f};
  floatx4 acc[4][4];
#pragma unroll
  for (int i = 0; i < 4; i++)
#pragma unroll
    for (int j = 0; j < 4; j++) acc[i][j] = zero;

  int NT = Kdim >> 6;   // K-tiles of 64 (18 for K=1152)

  // prologue: tile 0 both halves; vmcnt(4) -> H(0,0) resident
  stageA(0, 0); stageB(0, 0);
  stageA(0, 1); stageB(0, 1);
  asm volatile("s_waitcnt vmcnt(4)" ::: "memory");
  __builtin_amdgcn_s_barrier();

  for (int t = 0; t < NT; ++t) {
    const int abase = (t & 1) * 16384;
    const int arow = (wr * 64 + l16) * 32 + qoff;
    const int brow = (wc * 64 + l16) * 32 + qoff;

#pragma unroll
    for (int ks = 0; ks < 2; ++ks) {
      const int ab = abase + ks * 4096;
      const int bb = abase + 8192 + ks * 4096;
      bf16x8 af[4], bfr[4];
#pragma unroll
      for (int mf = 0; mf < 4; mf++)
        af[mf] = *(const bf16x8*)(S + ab + arow + mf * 512);
#pragma unroll
      for (int c = 0; c < 4; c++)
        bfr[c] = *(const bf16x8*)(S + bb + brow + c * 512);
      if (t + 1 < NT) { stageA(t + 1, ks); stageB(t + 1, ks); }
      __builtin_amdgcn_s_barrier();
      asm volatile("s_waitcnt lgkmcnt(0)" ::: "memory");
      __builtin_amdgcn_sched_barrier(0);
      __builtin_amdgcn_s_setprio(1);
#pragma unroll
      for (int c = 0; c < 4; c++)
#pragma unroll
        for (int mf = 0; mf < 4; mf++)
          acc[mf][c] = __builtin_amdgcn_mfma_f32_16x16x32_bf16(af[mf], bfr[c], acc[mf][c], 0, 0, 0);
      __builtin_amdgcn_s_setprio(0);
      if (t + 1 < NT)
        asm volatile("s_waitcnt vmcnt(4)" ::: "memory");
      else
        asm volatile("s_waitcnt vmcnt(0)" ::: "memory");
      __builtin_amdgcn_s_barrier();
    }
  }

  // epilogue
  float bv[4];
#pragma unroll
  for (int c = 0; c < 4; c++) bv[c] = bias[n0 + wc * 64 + c * 16 + l16];
#pragma unroll
  for (int mf = 0; mf < 4; mf++)
#pragma unroll
    for (int c = 0; c < 4; c++)
#pragma unroll
      for (int r = 0; r < 4; r++) {
        int row = m0 + wr * 64 + mf * 16 + quad * 4 + r;
        int col = n0 + wc * 64 + c * 16 + l16;
        float v = acc[mf][c][r] + bv[c];
        if constexpr (OUT_F32)
          ((float*)Cptr)[(size_t)row * Ncols + col] = v;
        else
          ((ushort_t*)Cptr)[(size_t)row * Ncols + col] = f2bf(v);
      }
}

// ---------------------------------------------------------------------------
// In-place per-head RMSNorm on bf16 (one wave per (row, head); 72 elems).
// Used only for K (Q norm fused into attention).
// ---------------------------------------------------------------------------
__global__ void rmsnorm_heads_kernel(ushort_t* __restrict__ p,
                                     const float* __restrict__ w,
                                     int rowstride) {
  int gw = blockIdx.x * 4 + (threadIdx.x >> 6);
  int lane = threadIdx.x & 63;
  int row = gw >> 4, h = gw & 15;
  ushort_t* base = p + (size_t)row * rowstride + h * HDIM;
  float v0 = bf2f(base[lane]);
  float v1 = (lane < 8) ? bf2f(base[64 + lane]) : 0.f;
  float ss = v0 * v0 + v1 * v1;
  for (int off = 1; off < 64; off <<= 1) ss += __shfl_xor(ss, off);
  float inv = rsqrtf(ss / 72.0f + 1e-6f);
  base[lane] = f2bf(v0 * inv * w[lane]);
  if (lane < 8) base[64 + lane] = f2bf(v1 * inv * w[64 + lane]);
}

// ---------------------------------------------------------------------------
// V [b,m,pair1,h,d] -> vT [b,h,d(80),m(512)] via LDS-tiled transpose.
// Coalesced 8-B global loads (rows of the head-slice), padded-stride LDS
// (84 ushorts), coalesced 8-B stores.
// d==72 row = ONES (gives P row-sums for free via the PV MFMA),
// d in (72,80) zeros. Grid (8 mchunks, 16 h, 4 b), 256 threads.
// ---------------------------------------------------------------------------
__global__ void vtrans_kernel(const ushort_t* __restrict__ kv16,
                              ushort_t* __restrict__ vT) {
  __shared__ ushort_t tile[64 * 84];
  int b = blockIdx.z, h = blockIdx.y, m0 = blockIdx.x * 64;
  int tid = threadIdx.x;
  int row = tid >> 2, sl = tid & 3;
  const ushort_t* src =
      kv16 + (size_t)(b * 512 + m0 + row) * 2304 + DIMC + h * HDIM;
#pragma unroll
  for (int k = 0; k < 5; k++) {
    int s = sl + 4 * k;            // segments of 4 ushorts; 18 segs = 72 elems
    if (s < 18) {
      uint2 v = *(const uint2*)(src + s * 4);
      *(uint2*)(tile + row * 84 + s * 4) = v;
    }
  }
  __syncthreads();
  size_t dbase = (size_t)((b * 16 + h) * 80) * 512 + m0;
#pragma unroll
  for (int it = 0; it < 5; it++) {
    int idx = it * 256 + tid;      // 1280 = 80 d-rows x 16 msegs, exact
    int d = idx >> 4, mseg = idx & 15;
    union { ushort_t s[4]; uint2 u; } pk;
    if (d < HDIM) {
      pk.s[0] = tile[(mseg * 4 + 0) * 84 + d];
      pk.s[1] = tile[(mseg * 4 + 1) * 84 + d];
      pk.s[2] = tile[(mseg * 4 + 2) * 84 + d];
      pk.s[3] = tile[(mseg * 4 + 3) * 84 + d];
    } else {
      ushort_t f = (d == HDIM) ? (ushort_t)0x3F80 : (ushort_t)0;  // 1.0 or 0
      pk.s[0] = pk.s[1] = pk.s[2] = pk.s[3] = f;
    }
    *(uint2*)(vT + dbase + (size_t)d * 512 + mseg * 4) = pk.u;
  }
}

// ---------------------------------------------------------------------------
// Flash cross-attention, fused Q-RMSNorm, no-max softmax (post-RMSNorm
// |s*scale| <= sqrt(72) ~ 8.5, exp2-safe in fp32). K/V tiles staged
// cooperatively into LDS via global_load_lds width 16 in MFMA-fragment
// chunk order: 22 chunks x 1KB, waves stage 6/6/5/5, 2 barriers per tile;
// all LDS accesses are conflict-free b128.
// P row-sums via ones-row (d=72) of vT through the PV MFMA.
// Ps is wave-private, XOR-swizzled.
// ---------------------------------------------------------------------------
__global__ __launch_bounds__(256, 4) void attn_kernel(
    const ushort_t* __restrict__ q16, const ushort_t* __restrict__ kv16,
    const ushort_t* __restrict__ vT, const int* __restrict__ seqlens,
    const float* __restrict__ qn_w, ushort_t* __restrict__ att) {
  __shared__ ushort_t KV[22 * 512];     // K chunks 0..11 (c*3+ks), V 12..21 (12+nf*2+ks)
  __shared__ ushort_t Ps[4][32 * 64];   // per-wave [row 32][m 64] swizzled
  int b = blockIdx.z, h = blockIdx.y, n0 = blockIdx.x * 128;
  int tid = threadIdx.x, wid = tid >> 6, lane = tid & 63;
  int quad = lane >> 4, l16 = lane & 15;
  int seqlen = seqlens[b];
  // 1/sqrt(72) * log2(e) folded into Q so that P = exp2(S)
  const float qscale = 0.11785113019775793f * 1.44269504088896f;

  ushort_t* Pw = &Ps[wid][0];

  // --- Q fragments + fused RMSNorm (qn_w and qscale folded in) ---
  bf16x8 qf[2][3];
  float ssq[2] = {0.f, 0.f};
  for (int rb = 0; rb < 2; rb++)
    for (int ks = 0; ks < 3; ks++) {
      if (ks == 2 && quad > 0) {
        qf[rb][ks] = (bf16x8){0, 0, 0, 0, 0, 0, 0, 0};
      } else {
        size_t off = ((size_t)(b * 4096 + n0 + wid * 32 + rb * 16 + l16)) * DIMC +
                     h * HDIM + ks * 32 + quad * 8;
        qf[rb][ks] = load_bf16x8(q16 + off);
        union { bf16x8 v; ushort_t s[8]; } e;
        e.v = qf[rb][ks];
        for (int j = 0; j < 8; j++) {
          float x = bf2f(e.s[j]);
          ssq[rb] += x * x;
        }
      }
    }
  for (int rb = 0; rb < 2; rb++) {
    ssq[rb] += __shfl_xor(ssq[rb], 16);
    ssq[rb] += __shfl_xor(ssq[rb], 32);
  }
  for (int rb = 0; rb < 2; rb++) {
    float inv = rsqrtf(ssq[rb] / 72.0f + 1e-6f) * qscale;
    for (int ks = 0; ks < 3; ks++) {
      if (ks == 2 && quad > 0) continue;
      float4 w0 = *(const float4*)(qn_w + ks * 32 + quad * 8);
      float4 w1 = *(const float4*)(qn_w + ks * 32 + quad * 8 + 4);
      union { bf16x8 v; ushort_t s[8]; } e;
      e.v = qf[rb][ks];
      e.s[0] = f2bf(bf2f(e.s[0]) * inv * w0.x);
      e.s[1] = f2bf(bf2f(e.s[1]) * inv * w0.y);
      e.s[2] = f2bf(bf2f(e.s[2]) * inv * w0.z);
      e.s[3] = f2bf(bf2f(e.s[3]) * inv * w0.w);
      e.s[4] = f2bf(bf2f(e.s[4]) * inv * w1.x);
      e.s[5] = f2bf(bf2f(e.s[5]) * inv * w1.y);
      e.s[6] = f2bf(bf2f(e.s[6]) * inv * w1.z);
      e.s[7] = f2bf(bf2f(e.s[7]) * inv * w1.w);
      qf[rb][ks] = e.v;
    }
  }

  floatx4 zero = {0.f, 0.f, 0.f, 0.f};
  floatx4 of[2][5];
  for (int rb = 0; rb < 2; rb++)
    for (int nf = 0; nf < 5; nf++) of[rb][nf] = zero;

  const size_t kvrow = (size_t)b * 512;
  const size_t vbase = (size_t)((b * 16 + h) * 80) * 512;

  int ntiles = (seqlen + 63) >> 6;
  for (int mt = 0; mt < ntiles; mt++) {
    int m0 = mt * 64;

    __syncthreads();   // previous tile's LDS reads done
    // cooperative staging: 22 chunks, wave w takes id = w, w+4, ...
    for (int id = wid; id < 22; id += 4) {
      const ushort_t* src;
      if (id < 12) {
        int c = (id * 11) >> 5;     // floor(id/3) for id<12: 0..3
        int ks = id - c * 3;
        src = kv16 + (size_t)(kvrow + m0 + c * 16 + l16) * 2304 + h * HDIM +
              ks * 32 + quad * 8;
      } else {
        int v = id - 12;
        int nf = v >> 1, ks = v & 1;
        src = vT + (vbase + (size_t)(nf * 16 + l16) * 512) + m0 + ks * 32 + quad * 8;
      }
      gload_lds16(src, KV + id * 512);
    }
    __syncthreads();   // staging complete

    // S = Q K^T from LDS K-frags (d >= 72 garbage x Q-zeros)
    floatx4 sf[2][4];
    for (int rb = 0; rb < 2; rb++)
      for (int c = 0; c < 4; c++) sf[rb][c] = zero;
    for (int c = 0; c < 4; c++)
      for (int ks = 0; ks < 3; ks++) {
        bf16x8 kf = *(const bf16x8*)(KV + (c * 3 + ks) * 512 + lane * 8);
        for (int rb = 0; rb < 2; rb++)
          sf[rb][c] = __builtin_amdgcn_mfma_f32_16x16x32_bf16(qf[rb][ks], kf, sf[rb][c], 0, 0, 0);
      }

    // P = exp2(S) masked; write to wave-private swizzled LDS
    for (int rb = 0; rb < 2; rb++)
      for (int c = 0; c < 4; c++) {
        bool valid = (m0 + c * 16 + l16) < seqlen;
        int col = (c * 16 + l16) ^ (quad * 16);
        int rowb = rb * 16 + quad * 4;
        for (int r = 0; r < 4; r++) {
          float pp = valid ? __builtin_amdgcn_exp2f(sf[rb][c][r]) : 0.f;
          Pw[(rowb + r) * 64 + col] = f2bf(pp);
        }
      }

    // O += P V from LDS V-frags (nf=4 includes ones-row d=72)
    for (int ks = 0; ks < 2; ks++) {
      bf16x8 pf[2];
      int g = ((ks * 2 + (quad >> 1)) * 16 + (quad & 1) * 8) ^ (((l16 >> 2) & 3) * 16);
      for (int rb = 0; rb < 2; rb++)
        pf[rb] = *(const bf16x8*)(Pw + (rb * 16 + l16) * 64 + g);
      for (int nf = 0; nf < 5; nf++) {
        bf16x8 vf = *(const bf16x8*)(KV + (12 + nf * 2 + ks) * 512 + lane * 8);
        for (int rb = 0; rb < 2; rb++)
          of[rb][nf] = __builtin_amdgcn_mfma_f32_16x16x32_bf16(pf[rb], vf, of[rb][nf], 0, 0, 0);
      }
    }
  }

  // normalize by the ones-column sums (d=72 -> nf=4, l16=8) and store
  for (int rb = 0; rb < 2; rb++) {
    float invl[4];
    for (int r = 0; r < 4; r++) {
      float lsum = __shfl(of[rb][4][r], (lane & 48) | 8);
      invl[r] = 1.0f / lsum;
    }
    for (int nf = 0; nf < 5; nf++) {
      int d = nf * 16 + l16;
      if (d < HDIM) {
        for (int r = 0; r < 4; r++) {
          size_t o = ((size_t)(b * 4096 + n0 + wid * 32 + rb * 16 + quad * 4 + r)) * DIMC +
                     h * HDIM + d;
          att[o] = f2bf(of[rb][nf][r] * invl[r]);
        }
      }
    }
  }
}

// ---------------------------------------------------------------------------
extern "C" void kernel_launch(void* const* d_in, const int* in_sizes, int n_in,
                              void* d_out, int out_size, void* d_ws, size_t ws_size,
                              hipStream_t stream) {
  const float* x      = (const float*)d_in[0];
  const float* cond   = (const float*)d_in[1];
  const int*   seqlen = (const int*)d_in[2];
  const float* q_w    = (const float*)d_in[3];
  const float* q_b    = (const float*)d_in[4];
  const float* kv_w   = (const float*)d_in[5];
  const float* kv_b   = (const float*)d_in[6];
  const float* proj_w = (const float*)d_in[7];
  const float* proj_b = (const float*)d_in[8];
  const float* qn_w   = (const float*)d_in[9];
  const float* kn_w   = (const float*)d_in[10];
  float* out = (float*)d_out;

  char* ws = (char*)d_ws;
  size_t o = 0;
  ushort_t* qwT    = (ushort_t*)(ws + o); o += (size_t)1152 * 1152 * 2;
  ushort_t* kvwT   = (ushort_t*)(ws + o); o += (size_t)2304 * 1152 * 2;
  ushort_t* pwT    = (ushort_t*)(ws + o); o += (size_t)1152 * 1152 * 2;
  ushort_t* q16    = (ushort_t*)(ws + o); o += (size_t)16384 * 1152 * 2;
  ushort_t* kv16   = (ushort_t*)(ws + o); o += (size_t)2048 * 2304 * 2;
  ushort_t* vT     = (ushort_t*)(ws + o); o += (size_t)64 * 80 * 512 * 2;
  ushort_t* att    = (ushort_t*)(ws + o); o += (size_t)16384 * 1152 * 2;
  ushort_t* x16    = (ushort_t*)(ws + o); o += (size_t)16384 * 1152 * 2;
  ushort_t* cond16 = (ushort_t*)(ws + o); o += (size_t)2048 * 1152 * 2;

  dim3 blk(256);

  // 0) activations fp32 -> bf16
  cvt_bf16_kernel<<<dim3((16384 * 1152 / 8 + 255) / 256), blk, 0, stream>>>(
      x, x16, 16384 * 1152 / 8);
  cvt_bf16_kernel<<<dim3((2048 * 1152 / 8 + 255) / 256), blk, 0, stream>>>(
      cond, cond16, 2048 * 1152 / 8);

  // 1) weight convert+transpose to bf16 [N][K]
  transpose_w_kernel<<<dim3(1152 / 64, 1152 / 64), blk, 0, stream>>>(q_w, qwT, 1152, 1152);
  transpose_w_kernel<<<dim3(1152 / 64, 2304 / 64), blk, 0, stream>>>(kv_w, kvwT, 1152, 2304);
  transpose_w_kernel<<<dim3(1152 / 64, 1152 / 64), blk, 0, stream>>>(proj_w, pwT, 1152, 1152);

  // 2+3) merged: Q = x @ q_w + q_b (1152 tiles) and KV = cond @ kv_w + kv_b
  //      (288 tiles) in one 1440-block dispatch (bf16 out)
  gemm128_kernel<false><<<dim3(1152 + 288), blk, 0, stream>>>(
      x16, qwT, q_b, q16, 9, 1152,
      cond16, kvwT, kv_b, kv16, 18, 2304,
      1152, 1152);

  // 4) RMSNorm k in place (pair-0 cols of kv16); q norm fused into attention
  rmsnorm_heads_kernel<<<dim3(2048 * 16 / 4), blk, 0, stream>>>(kv16, kn_w, 2304);

  // 5) V -> [b,h,d(80),m] with ones-row at d=72 (LDS-tiled, coalesced)
  vtrans_kernel<<<dim3(8, 16, 4), blk, 0, stream>>>(kv16, vT);

  // 6) attention (fused Q-RMSNorm, no-max softmax)
  attn_kernel<<<dim3(32, 16, 4), blk, 0, stream>>>(q16, kv16, vT, seqlen, qn_w, att);

  // 7) out = att @ proj_w + proj_b  (fp32 out), 1152 blocks
  gemm128_kernel<true><<<dim3(1152), blk, 0, stream>>>(
      att, pwT, proj_b, out, 9, 1152,
      att, pwT, proj_b, out, 9, 1152,
      1152, 1152);
}

// Round 6
// 360.172 us; speedup vs baseline: 1.0575x; 1.0575x over previous
//
#include <hip/hip_runtime.h>
#include <math.h>

typedef unsigned short ushort_t;
typedef __attribute__((ext_vector_type(4))) float floatx4;
typedef __attribute__((ext_vector_type(8))) short bf16x8;

#define DIMC 1152
#define NHEADS 16
#define HDIM 72

__device__ __forceinline__ ushort_t f2bf(float f) {
  unsigned u = __float_as_uint(f);
  u += 0x7FFFu + ((u >> 16) & 1u);      // round-to-nearest-even
  return (ushort_t)(u >> 16);
}
__device__ __forceinline__ float bf2f(ushort_t s) {
  return __uint_as_float(((unsigned)s) << 16);
}

__device__ __forceinline__ void gload_lds16(const ushort_t* g, ushort_t* l) {
  __builtin_amdgcn_global_load_lds(
      (const __attribute__((address_space(1))) unsigned int*)(const void*)g,
      (__attribute__((address_space(3))) unsigned int*)(void*)l, 16, 0, 0);
}

__device__ __forceinline__ bf16x8 load_bf16x8(const ushort_t* p) {
  union { bf16x8 v; uint4 u; } t;
  t.u = *(const uint4*)p;
  return t.v;
}

// ---------------------------------------------------------------------------
// Fused prep: {x, cond} fp32->bf16 cvt  +  3 weight transposes, one dispatch.
// Blocks: [0,9216) cvt x | [9216,10368) cvt cond | [10368,10692) q_w
// [10692,11340) kv_w | [11340,11664) proj_w.
// ---------------------------------------------------------------------------
__global__ void prep_kernel(const float* __restrict__ x, ushort_t* __restrict__ x16,
                            const float* __restrict__ cond, ushort_t* __restrict__ cond16,
                            const float* __restrict__ q_w, ushort_t* __restrict__ qwT,
                            const float* __restrict__ kv_w, ushort_t* __restrict__ kvwT,
                            const float* __restrict__ proj_w, ushort_t* __restrict__ pwT) {
  __shared__ ushort_t tile[64 * 80];
  int blk = blockIdx.x;
  int tid = threadIdx.x;

  if (blk < 10368) {   // cvt path (exact coverage, no bounds check)
    const float* src; ushort_t* dst; int i;
    if (blk < 9216) { src = x; dst = x16; i = blk * 256 + tid; }
    else            { src = cond; dst = cond16; i = (blk - 9216) * 256 + tid; }
    float4 f0 = ((const float4*)src)[2 * (size_t)i];
    float4 f1 = ((const float4*)src)[2 * (size_t)i + 1];
    union { ushort_t s[8]; uint4 u; } t;
    t.s[0] = f2bf(f0.x); t.s[1] = f2bf(f0.y); t.s[2] = f2bf(f0.z); t.s[3] = f2bf(f0.w);
    t.s[4] = f2bf(f1.x); t.s[5] = f2bf(f1.y); t.s[6] = f2bf(f1.z); t.s[7] = f2bf(f1.w);
    ((uint4*)dst)[i] = t.u;
    return;
  }

  // transpose path: W [K=1152][N] fp32 -> Wt [N][1152] bf16, 64x64 tiles
  const float* W; ushort_t* Wt; int N, idx;
  if (blk < 10692)      { W = q_w;    Wt = qwT;  N = 1152; idx = blk - 10368; }
  else if (blk < 11340) { W = kv_w;   Wt = kvwT; N = 2304; idx = blk - 10692; }
  else                  { W = proj_w; Wt = pwT;  N = 1152; idx = blk - 11340; }
  const int K = 1152;
  int k0 = (idx % 18) * 64, n0 = (idx / 18) * 64;

  int kl = tid >> 4, n4 = tid & 15;
  for (int rr = 0; rr < 4; rr++) {
    int k = kl + rr * 16;
    float4 f = *(const float4*)(W + (size_t)(k0 + k) * N + n0 + n4 * 4);
    tile[(n4 * 4 + 0) * 80 + k] = f2bf(f.x);
    tile[(n4 * 4 + 1) * 80 + k] = f2bf(f.y);
    tile[(n4 * 4 + 2) * 80 + k] = f2bf(f.z);
    tile[(n4 * 4 + 3) * 80 + k] = f2bf(f.w);
  }
  __syncthreads();
  int nl = tid >> 2, kq = tid & 3;
  uint4 v0 = *(const uint4*)(tile + nl * 80 + kq * 16);
  uint4 v1 = *(const uint4*)(tile + nl * 80 + kq * 16 + 8);
  *(uint4*)(Wt + (size_t)(n0 + nl) * K + k0 + kq * 16) = v0;
  *(uint4*)(Wt + (size_t)(n0 + nl) * K + k0 + kq * 16 + 8) = v1;
}

// ---------------------------------------------------------------------------
// 128x128 GEMM, BK=64, ks-split 2-phase schedule. 256 threads (4 waves 2x2,
// per-wave 64x64 = acc[4][4]). LDS 64 KiB = 2 bufs -> 2 blocks/CU.
// Phase ks: 8 ds_read_b128 + 16 MFMA; stage H(t+1,ks); counted vmcnt(4)
// every phase (retires the slab issued one full tile earlier). XOR-swizzled
// LDS (pre-swizzled global src for linear global_load_lds dst).
// Two problem segments routed by block id. Grid %8 == 0 for XCD swizzle.
// ---------------------------------------------------------------------------
template <bool OUT_F32>
__global__ __launch_bounds__(256, 2) void gemm128_kernel(
    const ushort_t* __restrict__ A0, const ushort_t* __restrict__ Bt0,
    const float* __restrict__ bias0, void* __restrict__ C0,
    int NTn0, int Ncols0,
    const ushort_t* __restrict__ A1, const ushort_t* __restrict__ Bt1,
    const float* __restrict__ bias1, void* __restrict__ C1,
    int NTn1, int Ncols1,
    int nblk0, int Kdim) {
  __shared__ ushort_t S[32768];  // 64 KiB: buf*16384 + ks*4096 + {A:0, B:8192}

  int lin = blockIdx.x;
  int cpx = gridDim.x >> 3;
  int wg = (lin & 7) * cpx + (lin >> 3);   // XCD-contiguous chunks

  const ushort_t* Aseg; const ushort_t* Bseg;
  const float* bias; void* Cptr; int NTn, Ncols;
  if (wg < nblk0) {
    Aseg = A0; Bseg = Bt0; bias = bias0; Cptr = C0; NTn = NTn0; Ncols = Ncols0;
  } else {
    wg -= nblk0;
    Aseg = A1; Bseg = Bt1; bias = bias1; Cptr = C1; NTn = NTn1; Ncols = Ncols1;
  }
  int mt = wg / NTn, nt = wg % NTn;
  int m0 = mt * 128, n0 = nt * 128;

  int tid = threadIdx.x;
  int wid = tid >> 6, lane = tid & 63, quad = lane >> 4, l16 = lane & 15;
  int wr = wid >> 1, wc = wid & 1;
  const int qoff = (quad * 8) ^ ((l16 & 8) << 1);  // swizzled read col (ushorts)

  const int srow = tid >> 2;                                   // 0..63
  const int scol = ((tid & 3) * 8) ^ ((tid & 32) ? 16 : 0);    // ushorts
  const ushort_t* Abase = Aseg + (size_t)m0 * Kdim;
  const ushort_t* Bbase = Bseg + (size_t)n0 * Kdim;

  auto stageA = [&](int t, int ks) {
    const ushort_t* src = Abase + (size_t)srow * Kdim + t * 64 + ks * 32 + scol;
    ushort_t* dst = S + (t & 1) * 16384 + ks * 4096 + (tid >> 6) * 512;
    gload_lds16(src, dst);
    gload_lds16(src + (size_t)64 * Kdim, dst + 2048);
  };
  auto stageB = [&](int t, int ks) {
    const ushort_t* src = Bbase + (size_t)srow * Kdim + t * 64 + ks * 32 + scol;
    ushort_t* dst = S + (t & 1) * 16384 + 8192 + ks * 4096 + (tid >> 6) * 512;
    gload_lds16(src, dst);
    gload_lds16(src + (size_t)64 * Kdim, dst + 2048);
  };

  floatx4 zero = {0.f, 0.f, 0.f, 0.f};
  floatx4 acc[4][4];
#pragma unroll
  for (int i = 0; i < 4; i++)
#pragma unroll
    for (int j = 0; j < 4; j++) acc[i][j] = zero;

  int NT = Kdim >> 6;   // 18 for K=1152

  stageA(0, 0); stageB(0, 0);
  stageA(0, 1); stageB(0, 1);
  asm volatile("s_waitcnt vmcnt(4)" ::: "memory");
  __builtin_amdgcn_s_barrier();

  for (int t = 0; t < NT; ++t) {
    const int abase = (t & 1) * 16384;
    const int arow = (wr * 64 + l16) * 32 + qoff;
    const int brow = (wc * 64 + l16) * 32 + qoff;

#pragma unroll
    for (int ks = 0; ks < 2; ++ks) {
      const int ab = abase + ks * 4096;
      const int bb = abase + 8192 + ks * 4096;
      bf16x8 af[4], bfr[4];
#pragma unroll
      for (int mf = 0; mf < 4; mf++)
        af[mf] = *(const bf16x8*)(S + ab + arow + mf * 512);
#pragma unroll
      for (int c = 0; c < 4; c++)
        bfr[c] = *(const bf16x8*)(S + bb + brow + c * 512);
      if (t + 1 < NT) { stageA(t + 1, ks); stageB(t + 1, ks); }
      __builtin_amdgcn_s_barrier();
      asm volatile("s_waitcnt lgkmcnt(0)" ::: "memory");
      __builtin_amdgcn_sched_barrier(0);
      __builtin_amdgcn_s_setprio(1);
#pragma unroll
      for (int c = 0; c < 4; c++)
#pragma unroll
        for (int mf = 0; mf < 4; mf++)
          acc[mf][c] = __builtin_amdgcn_mfma_f32_16x16x32_bf16(af[mf], bfr[c], acc[mf][c], 0, 0, 0);
      __builtin_amdgcn_s_setprio(0);
      if (t + 1 < NT)
        asm volatile("s_waitcnt vmcnt(4)" ::: "memory");
      else
        asm volatile("s_waitcnt vmcnt(0)" ::: "memory");
      __builtin_amdgcn_s_barrier();
    }
  }

  float bv[4];
#pragma unroll
  for (int c = 0; c < 4; c++) bv[c] = bias[n0 + wc * 64 + c * 16 + l16];
#pragma unroll
  for (int mf = 0; mf < 4; mf++)
#pragma unroll
    for (int c = 0; c < 4; c++)
#pragma unroll
      for (int r = 0; r < 4; r++) {
        int row = m0 + wr * 64 + mf * 16 + quad * 4 + r;
        int col = n0 + wc * 64 + c * 16 + l16;
        float v = acc[mf][c][r] + bv[c];
        if constexpr (OUT_F32)
          ((float*)Cptr)[(size_t)row * Ncols + col] = v;
        else
          ((ushort_t*)Cptr)[(size_t)row * Ncols + col] = f2bf(v);
      }
}

// ---------------------------------------------------------------------------
// Fused: K-RMSNorm (blocks [0,8192)) + V transpose (blocks [8192,8704)).
// rms: one wave per (row, head), in-place on kv16 pair-0.
// vtrans: V -> vT [b,h,d(80),m(512)] via LDS tile; d==72 row = ONES,
// d in (72,80) zeros.
// ---------------------------------------------------------------------------
__global__ void rmsvt_kernel(ushort_t* __restrict__ kv16,
                             const float* __restrict__ kn_w,
                             ushort_t* __restrict__ vT) {
  __shared__ ushort_t tile[64 * 84];
  int blk = blockIdx.x;
  int tid = threadIdx.x;

  if (blk < 8192) {   // RMSNorm on K
    int gw = blk * 4 + (tid >> 6);
    int lane = tid & 63;
    int row = gw >> 4, h = gw & 15;
    ushort_t* base = kv16 + (size_t)row * 2304 + h * HDIM;
    float v0 = bf2f(base[lane]);
    float v1 = (lane < 8) ? bf2f(base[64 + lane]) : 0.f;
    float ss = v0 * v0 + v1 * v1;
    for (int off = 1; off < 64; off <<= 1) ss += __shfl_xor(ss, off);
    float inv = rsqrtf(ss / 72.0f + 1e-6f);
    base[lane] = f2bf(v0 * inv * kn_w[lane]);
    if (lane < 8) base[64 + lane] = f2bf(v1 * inv * kn_w[64 + lane]);
    return;
  }

  int idx = blk - 8192;             // 0..511
  int m0 = (idx & 7) * 64, h = (idx >> 3) & 15, b = idx >> 7;
  int row = tid >> 2, sl = tid & 3;
  const ushort_t* src =
      kv16 + (size_t)(b * 512 + m0 + row) * 2304 + DIMC + h * HDIM;
#pragma unroll
  for (int k = 0; k < 5; k++) {
    int s = sl + 4 * k;
    if (s < 18) {
      uint2 v = *(const uint2*)(src + s * 4);
      *(uint2*)(tile + row * 84 + s * 4) = v;
    }
  }
  __syncthreads();
  size_t dbase = (size_t)((b * 16 + h) * 80) * 512 + m0;
#pragma unroll
  for (int it = 0; it < 5; it++) {
    int i2 = it * 256 + tid;
    int d = i2 >> 4, mseg = i2 & 15;
    union { ushort_t s[4]; uint2 u; } pk;
    if (d < HDIM) {
      pk.s[0] = tile[(mseg * 4 + 0) * 84 + d];
      pk.s[1] = tile[(mseg * 4 + 1) * 84 + d];
      pk.s[2] = tile[(mseg * 4 + 2) * 84 + d];
      pk.s[3] = tile[(mseg * 4 + 3) * 84 + d];
    } else {
      ushort_t f = (d == HDIM) ? (ushort_t)0x3F80 : (ushort_t)0;
      pk.s[0] = pk.s[1] = pk.s[2] = pk.s[3] = f;
    }
    *(uint2*)(vT + dbase + (size_t)d * 512 + mseg * 4) = pk.u;
  }
}

// ---------------------------------------------------------------------------
// Flash cross-attention, fused Q-RMSNorm, no-max softmax.
// ROUND-6 CHANGE (attn was VALU-bound: 48% VALUBusy, 18% Mfma):
// SWAPPED QK^T: sf = mfma(K, Q) gives S^T — each lane holds 4 CONSECUTIVE
// k-values per (c,quad) for one q-row (q = rb*16+l16). P-phase becomes:
// 32 exp2 + 16 v_cvt_pk_bf16_f32 + 8 ds_write_b64 (was ~128 f2bf ops +
// 32 ds_write_u16); masking hoisted behind wave-uniform partial-tile test.
// P stored [q(32)][k-pairs(32 u32)] per wave, word-XOR swizzle
// ((l16&7)<<2): write b64 2-way conflicts (free), read b128 2-way (free).
// PV reads pf as 4 swizzled ds_read_b128 in exact A-frag k-order.
// PV MFMA, ones-row l-sum, epilogue unchanged (same D layout).
// ---------------------------------------------------------------------------
__global__ __launch_bounds__(256, 4) void attn_kernel(
    const ushort_t* __restrict__ q16, const ushort_t* __restrict__ kv16,
    const ushort_t* __restrict__ vT, const int* __restrict__ seqlens,
    const float* __restrict__ qn_w, ushort_t* __restrict__ att) {
  __shared__ ushort_t KV[22 * 512];            // K: 0..11 (c*3+ks), V: 12..21
  __shared__ __align__(16) unsigned Ps[4][32 * 32];  // per-wave [q32][kpair32]
  int b = blockIdx.z, h = blockIdx.y, n0 = blockIdx.x * 128;
  int tid = threadIdx.x, wid = tid >> 6, lane = tid & 63;
  int quad = lane >> 4, l16 = lane & 15;
  int seqlen = seqlens[b];
  const float qscale = 0.11785113019775793f * 1.44269504088896f;

  unsigned* Pw = &Ps[wid][0];
  const int xorm = (l16 & 7) << 2;

  // --- Q fragments + fused RMSNorm (qn_w and qscale folded in) ---
  bf16x8 qf[2][3];
  float ssq[2] = {0.f, 0.f};
  for (int rb = 0; rb < 2; rb++)
    for (int ks = 0; ks < 3; ks++) {
      if (ks == 2 && quad > 0) {
        qf[rb][ks] = (bf16x8){0, 0, 0, 0, 0, 0, 0, 0};
      } else {
        size_t off = ((size_t)(b * 4096 + n0 + wid * 32 + rb * 16 + l16)) * DIMC +
                     h * HDIM + ks * 32 + quad * 8;
        qf[rb][ks] = load_bf16x8(q16 + off);
        union { bf16x8 v; ushort_t s[8]; } e;
        e.v = qf[rb][ks];
        for (int j = 0; j < 8; j++) {
          float xv = bf2f(e.s[j]);
          ssq[rb] += xv * xv;
        }
      }
    }
  for (int rb = 0; rb < 2; rb++) {
    ssq[rb] += __shfl_xor(ssq[rb], 16);
    ssq[rb] += __shfl_xor(ssq[rb], 32);
  }
  for (int rb = 0; rb < 2; rb++) {
    float inv = rsqrtf(ssq[rb] / 72.0f + 1e-6f) * qscale;
    for (int ks = 0; ks < 3; ks++) {
      if (ks == 2 && quad > 0) continue;
      float4 w0 = *(const float4*)(qn_w + ks * 32 + quad * 8);
      float4 w1 = *(const float4*)(qn_w + ks * 32 + quad * 8 + 4);
      union { bf16x8 v; ushort_t s[8]; } e;
      e.v = qf[rb][ks];
      e.s[0] = f2bf(bf2f(e.s[0]) * inv * w0.x);
      e.s[1] = f2bf(bf2f(e.s[1]) * inv * w0.y);
      e.s[2] = f2bf(bf2f(e.s[2]) * inv * w0.z);
      e.s[3] = f2bf(bf2f(e.s[3]) * inv * w0.w);
      e.s[4] = f2bf(bf2f(e.s[4]) * inv * w1.x);
      e.s[5] = f2bf(bf2f(e.s[5]) * inv * w1.y);
      e.s[6] = f2bf(bf2f(e.s[6]) * inv * w1.z);
      e.s[7] = f2bf(bf2f(e.s[7]) * inv * w1.w);
      qf[rb][ks] = e.v;
    }
  }

  floatx4 zero = {0.f, 0.f, 0.f, 0.f};
  floatx4 of[2][5];
  for (int rb = 0; rb < 2; rb++)
    for (int nf = 0; nf < 5; nf++) of[rb][nf] = zero;

  const size_t kvrow = (size_t)b * 512;
  const size_t vbase = (size_t)((b * 16 + h) * 80) * 512;

  int ntiles = (seqlen + 63) >> 6;
  for (int mt = 0; mt < ntiles; mt++) {
    int m0 = mt * 64;

    __syncthreads();   // previous tile's LDS reads done
    for (int id = wid; id < 22; id += 4) {
      const ushort_t* src;
      if (id < 12) {
        int c = (id * 11) >> 5;     // floor(id/3)
        int ks = id - c * 3;
        src = kv16 + (size_t)(kvrow + m0 + c * 16 + l16) * 2304 + h * HDIM +
              ks * 32 + quad * 8;
      } else {
        int v = id - 12;
        int nf = v >> 1, ks = v & 1;
        src = vT + (vbase + (size_t)(nf * 16 + l16) * 512) + m0 + ks * 32 + quad * 8;
      }
      gload_lds16(src, KV + id * 512);
    }
    __syncthreads();   // staging complete

    // S^T = K Q^T (swapped): sf[rb][c][r] = S[k=c*16+quad*4+r][q=rb*16+l16]
    floatx4 sf[2][4];
    for (int rb = 0; rb < 2; rb++)
      for (int c = 0; c < 4; c++) sf[rb][c] = zero;
    for (int c = 0; c < 4; c++)
      for (int ks = 0; ks < 3; ks++) {
        bf16x8 kf = *(const bf16x8*)(KV + (c * 3 + ks) * 512 + lane * 8);
        for (int rb = 0; rb < 2; rb++)
          sf[rb][c] = __builtin_amdgcn_mfma_f32_16x16x32_bf16(kf, qf[rb][ks], sf[rb][c], 0, 0, 0);
      }

    // P = exp2(S) masked; pack k-pairs (cvt_pk) -> swizzled [q][k] LDS
    bool partial = (m0 + 64) > seqlen;
    for (int rb = 0; rb < 2; rb++) {
      unsigned* prow = Pw + (rb * 16 + l16) * 32;
      for (int c = 0; c < 4; c++) {
        float p0 = __builtin_amdgcn_exp2f(sf[rb][c][0]);
        float p1 = __builtin_amdgcn_exp2f(sf[rb][c][1]);
        float p2 = __builtin_amdgcn_exp2f(sf[rb][c][2]);
        float p3 = __builtin_amdgcn_exp2f(sf[rb][c][3]);
        if (partial) {
          int kabs = m0 + c * 16 + quad * 4;
          p0 = (kabs < seqlen) ? p0 : 0.f;
          p1 = (kabs + 1 < seqlen) ? p1 : 0.f;
          p2 = (kabs + 2 < seqlen) ? p2 : 0.f;
          p3 = (kabs + 3 < seqlen) ? p3 : 0.f;
        }
        unsigned w0, w1;
        asm("v_cvt_pk_bf16_f32 %0, %1, %2" : "=v"(w0) : "v"(p0), "v"(p1));
        asm("v_cvt_pk_bf16_f32 %0, %1, %2" : "=v"(w1) : "v"(p2), "v"(p3));
        uint2 pw2; pw2.x = w0; pw2.y = w1;
        *(uint2*)(prow + ((8 * c + 2 * quad) ^ xorm)) = pw2;
      }
    }

    // O += P V (pf read as swizzled b128 in A-frag k-order)
    for (int ks = 0; ks < 2; ks++) {
      bf16x8 pf[2];
      for (int rb = 0; rb < 2; rb++) {
        const unsigned* prow = Pw + (rb * 16 + l16) * 32;
        pf[rb] = *(const bf16x8*)(prow + ((ks * 16 + quad * 4) ^ xorm));
      }
      for (int nf = 0; nf < 5; nf++) {
        bf16x8 vf = *(const bf16x8*)(KV + (12 + nf * 2 + ks) * 512 + lane * 8);
        for (int rb = 0; rb < 2; rb++)
          of[rb][nf] = __builtin_amdgcn_mfma_f32_16x16x32_bf16(pf[rb], vf, of[rb][nf], 0, 0, 0);
      }
    }
  }

  // normalize by the ones-column sums (d=72 -> nf=4, l16=8) and store
  for (int rb = 0; rb < 2; rb++) {
    float invl[4];
    for (int r = 0; r < 4; r++) {
      float lsum = __shfl(of[rb][4][r], (lane & 48) | 8);
      invl[r] = 1.0f / lsum;
    }
    for (int nf = 0; nf < 5; nf++) {
      int d = nf * 16 + l16;
      if (d < HDIM) {
        for (int r = 0; r < 4; r++) {
          size_t o = ((size_t)(b * 4096 + n0 + wid * 32 + rb * 16 + quad * 4 + r)) * DIMC +
                     h * HDIM + d;
          att[o] = f2bf(of[rb][nf][r] * invl[r]);
        }
      }
    }
  }
}

// ---------------------------------------------------------------------------
extern "C" void kernel_launch(void* const* d_in, const int* in_sizes, int n_in,
                              void* d_out, int out_size, void* d_ws, size_t ws_size,
                              hipStream_t stream) {
  const float* x      = (const float*)d_in[0];
  const float* cond   = (const float*)d_in[1];
  const int*   seqlen = (const int*)d_in[2];
  const float* q_w    = (const float*)d_in[3];
  const float* q_b    = (const float*)d_in[4];
  const float* kv_w   = (const float*)d_in[5];
  const float* kv_b   = (const float*)d_in[6];
  const float* proj_w = (const float*)d_in[7];
  const float* proj_b = (const float*)d_in[8];
  const float* qn_w   = (const float*)d_in[9];
  const float* kn_w   = (const float*)d_in[10];
  float* out = (float*)d_out;

  char* ws = (char*)d_ws;
  size_t o = 0;
  ushort_t* qwT    = (ushort_t*)(ws + o); o += (size_t)1152 * 1152 * 2;
  ushort_t* kvwT   = (ushort_t*)(ws + o); o += (size_t)2304 * 1152 * 2;
  ushort_t* pwT    = (ushort_t*)(ws + o); o += (size_t)1152 * 1152 * 2;
  ushort_t* q16    = (ushort_t*)(ws + o); o += (size_t)16384 * 1152 * 2;
  ushort_t* kv16   = (ushort_t*)(ws + o); o += (size_t)2048 * 2304 * 2;
  ushort_t* vT     = (ushort_t*)(ws + o); o += (size_t)64 * 80 * 512 * 2;
  ushort_t* att    = (ushort_t*)(ws + o); o += (size_t)16384 * 1152 * 2;
  ushort_t* x16    = (ushort_t*)(ws + o); o += (size_t)16384 * 1152 * 2;
  ushort_t* cond16 = (ushort_t*)(ws + o); o += (size_t)2048 * 1152 * 2;

  dim3 blk(256);

  // 1) fused prep: cvt x/cond + 3 weight transposes (one dispatch)
  prep_kernel<<<dim3(11664), blk, 0, stream>>>(
      x, x16, cond, cond16, q_w, qwT, kv_w, kvwT, proj_w, pwT);

  // 2) merged: Q = x @ q_w + q_b (1152 tiles) and KV = cond @ kv_w + kv_b
  //    (288 tiles) in one 1440-block dispatch (bf16 out)
  gemm128_kernel<false><<<dim3(1152 + 288), blk, 0, stream>>>(
      x16, qwT, q_b, q16, 9, 1152,
      cond16, kvwT, kv_b, kv16, 18, 2304,
      1152, 1152);

  // 3) fused K-RMSNorm + V-transpose (one dispatch)
  rmsvt_kernel<<<dim3(8192 + 512), blk, 0, stream>>>(kv16, kn_w, vT);

  // 4) attention (fused Q-RMSNorm, swapped QK^T, packed in-LDS P)
  attn_kernel<<<dim3(32, 16, 4), blk, 0, stream>>>(q16, kv16, vT, seqlen, qn_w, att);

  // 5) out = att @ proj_w + proj_b  (fp32 out), 1152 blocks
  gemm128_kernel<true><<<dim3(1152), blk, 0, stream>>>(
      att, pwT, proj_b, out, 9, 1152,
      att, pwT, proj_b, out, 9, 1152,
      1152, 1152);
}